// Round 7
// baseline (1668.793 us; speedup 1.0000x reference)
//
#include <hip/hip_runtime.h>
#include <cstddef>

// Problem constants (match reference: N=4096, D=2048, B=64)
#define NN 4096
#define DD 2048
#define BB 64
#define RPB 8                   // rows per block (persistent kernel)
#define NBLK (NN / RPB)         // 512 blocks = 2/CU on 256 CUs (co-resident)

constexpr float kAT     = 0.3f;
constexpr float kDSBETA = 1e-4f;
constexpr float kEB     = 0.5f;
constexpr float kEN     = 0.005f;   // 0.01 * E_B
constexpr float kEPS    = 0.01f;

__device__ __forceinline__ float wave_sum_f(float v) {
#pragma unroll
    for (int o = 32; o; o >>= 1) v += __shfl_xor(v, o, 64);
    return v;
}
__device__ __forceinline__ double wave_sum_d(double v) {
#pragma unroll
    for (int o = 32; o; o >>= 1) v += __shfl_xor(v, o, 64);
    return v;
}
__device__ __forceinline__ float wave_max_f(float v) {
#pragma unroll
    for (int o = 32; o; o >>= 1) v = fmaxf(v, __shfl_xor(v, o, 64));
    return v;
}
__device__ __forceinline__ float wave_min_f(float v) {
#pragma unroll
    for (int o = 32; o; o >>= 1) v = fminf(v, __shfl_xor(v, o, 64));
    return v;
}
__device__ __forceinline__ unsigned long long wave_max_u64(unsigned long long v) {
#pragma unroll
    for (int o = 32; o; o >>= 1) {
        const unsigned long long u = __shfl_xor(v, o, 64);
        v = (u > v) ? u : v;
    }
    return v;
}

// Decide whether `neighbors` arrived as byte-bools or int32.
__global__ void detect_nb(const unsigned char* __restrict__ nb, unsigned* __restrict__ flag) {
    unsigned v = 0;
    const int i0 = threadIdx.x * 256;
    for (int i = 0; i < 256; i++) {
        const int idx = i0 + i;
        if ((idx & 3) != 0) v |= nb[idx];
    }
    if (v != 0) atomicOr(flag, 1u);
}

// ---------------------------------------------------------------------------
// Persistent kernel, plain launch (graph-capturable). All 64 steps, one
// dispatch. Sync protocol per step (write-once / single-reader / broadcast):
//   1. every block RELEASE-stores its local argmax key to keys[t*512+bid]
//      (own slot: no RMW, no sharing; keys are never 0 since act > 0)
//   2. block 0 wave 0 polls all 512 slots (relaxed), wave-maxes, publishes
//      winner key to 8 line-padded broadcast copies (RELEASE)
//   3. every block polls one broadcast copy (1 thread, s_sleep backoff);
//      the key IS the payload, so no waiter-side fence is needed.
// ---------------------------------------------------------------------------
__global__ __launch_bounds__(256, 2) void som_persist(
    const float* __restrict__ x,            // B x D
    const float* __restrict__ W0,           // N x D initial
    const float* __restrict__ M0,           // N x D initial
    const float* __restrict__ R0,           // N x D initial
    const unsigned char* __restrict__ nbb,  // N x N (byte or int32 per *flag)
    const unsigned* __restrict__ flag,
    float* __restrict__ Wout,               // N x D final (d_out)
    unsigned long long* __restrict__ keys,  // BB x NBLK write-once key slots
    unsigned long long* __restrict__ wkey)  // BB x 8 broadcast copies, 64B apart
{
    const int tid  = threadIdx.x;
    const int wid  = tid >> 6;
    const int lane = tid & 63;
    const int bid  = (int)blockIdx.x;
    const int n0   = bid * RPB;
    const int col  = tid * 8;

    __shared__ double sdd[2][RPB][4];
    __shared__ float  sf[3][4];
    __shared__ unsigned long long skk[RPB];
    __shared__ unsigned long long sKey;

    const bool nb_byte = (*flag != 0);

    float w[RPB][8], r[RPB][8], m[RPB][8], xcur[8], xnext[8];

#pragma unroll
    for (int row = 0; row < RPB; ++row) {
        const size_t base = (size_t)(n0 + row) * DD + col;
        *(float4*)(&w[row][0]) = *(const float4*)(W0 + base);
        *(float4*)(&w[row][4]) = *(const float4*)(W0 + base + 4);
        *(float4*)(&r[row][0]) = *(const float4*)(R0 + base);
        *(float4*)(&r[row][4]) = *(const float4*)(R0 + base + 4);
        *(float4*)(&m[row][0]) = *(const float4*)(M0 + base);
        *(float4*)(&m[row][4]) = *(const float4*)(M0 + base + 4);
    }
    *(float4*)(xcur)     = *(const float4*)(x + col);
    *(float4*)(xcur + 4) = *(const float4*)(x + col + 4);

    // block-local argmax over this block's 8 rows vs xcur -> own key slot
    auto post_key = [&](int slot) {
#pragma unroll
        for (int row = 0; row < RPB; ++row) {
            double pd = 0.0, ps = 0.0;
#pragma unroll
            for (int j = 0; j < 8; ++j) {
                const double d  = (double)xcur[j] - (double)w[row][j];
                const double rj = (double)r[row][j];
                pd += rj * d * d;
                ps += rj;
            }
            pd = wave_sum_d(pd); ps = wave_sum_d(ps);
            if (lane == 0) { sdd[0][row][wid] = pd; sdd[1][row][wid] = ps; }
        }
        __syncthreads();
        if (tid < RPB) {
            const int row = tid;
            const double td = sdd[0][row][0] + sdd[0][row][1] + sdd[0][row][2] + sdd[0][row][3];
            const double tr = sdd[1][row][0] + sdd[1][row][1] + sdd[1][row][2] + sdd[1][row][3];
            const double act = tr / (tr + td + 1e-7);
            const unsigned long long ab = (unsigned long long)__double_as_longlong(act);
            skk[row] = (ab & ~0xFFFULL) | (unsigned long long)(4095 - (n0 + row));
        }
        __syncthreads();
        if (tid == 0) {
            unsigned long long k = skk[0];
#pragma unroll
            for (int i = 1; i < RPB; ++i) k = (skk[i] > k) ? skk[i] : k;
            __hip_atomic_store(&keys[(size_t)slot * NBLK + bid], k,
                               __ATOMIC_RELEASE, __HIP_MEMORY_SCOPE_AGENT);
        }
        __syncthreads();
    };

    post_key(0);
    // prefetch x for step 1 while the first sync settles
    *(float4*)(xnext)     = *(const float4*)(x + DD + col);
    *(float4*)(xnext + 4) = *(const float4*)(x + DD + 4 + col);

    for (int t = 0; t < BB; ++t) {
        // ---- monitor duty: block 0 wave 0 collects + publishes winner ----
        if (bid == 0 && wid == 0) {
            const unsigned long long* kt = keys + (size_t)t * NBLK;
            int it = 0;
            while (true) {
                bool ok = true;
                unsigned long long mx = 0;
#pragma unroll
                for (int i = 0; i < NBLK / 64; ++i) {
                    const unsigned long long v = __hip_atomic_load(
                        &kt[lane + 64 * i], __ATOMIC_RELAXED, __HIP_MEMORY_SCOPE_AGENT);
                    ok &= (v != 0ULL);
                    mx = (v > mx) ? v : mx;
                }
                if (__all(ok) || ++it > 4000000) {
                    mx = wave_max_u64(mx);
                    if (lane < 8)
                        __hip_atomic_store(&wkey[((size_t)t * 8 + lane) * 8], mx,
                                           __ATOMIC_RELEASE, __HIP_MEMORY_SCOPE_AGENT);
                    break;
                }
                __builtin_amdgcn_s_sleep(1);
            }
        }
        // ---- all blocks: wait for the broadcast key ----
        if (tid == 0) {
            unsigned long long k = 0;
            int it = 0;
            while (true) {
                k = __hip_atomic_load(&wkey[((size_t)t * 8 + (bid & 7)) * 8],
                                      __ATOMIC_RELAXED, __HIP_MEMORY_SCOPE_AGENT);
                if (k != 0ULL || ++it > 4000000) break;   // never hang
                __builtin_amdgcn_s_sleep(4);
            }
            sKey = k;
        }
        __syncthreads();
        const unsigned long long k = sKey;
        __syncthreads();
        const double act_w = __longlong_as_double((long long)(k & ~0xFFFULL));
        const int winner   = 4095 - (int)(k & 0xFFFULL);

        if (act_w >= (double)kAT) {     // do_upd (grid-uniform)
            // fetch this block's 8-entry segment of the winner's nb row in one
            // broadcast load instead of 8 dependent byte loads
            bool isnb[RPB];
            if (nb_byte) {
                const unsigned long long nbw =
                    *(const unsigned long long*)(nbb + (size_t)winner * NN + n0);
#pragma unroll
                for (int i = 0; i < RPB; ++i) isnb[i] = ((nbw >> (8 * i)) & 0xFFULL) != 0;
            } else {
                const uint4* p = (const uint4*)((const int*)nbb + (size_t)winner * NN + n0);
                const uint4 a = p[0], b = p[1];
                isnb[0] = a.x != 0; isnb[1] = a.y != 0; isnb[2] = a.z != 0; isnb[3] = a.w != 0;
                isnb[4] = b.x != 0; isnb[5] = b.y != 0; isnb[6] = b.z != 0; isnb[7] = b.w != 0;
            }
#pragma unroll
            for (int row = 0; row < RPB; ++row) {
                const int n = n0 + row;
                const float lr = (n == winner) ? kEB : (isnb[row] ? kEN : 0.0f);
                if (lr != 0.0f) {       // block-uniform per row
                    const float c1 = lr * kDSBETA;
                    const float c2 = 1.0f - c1;
                    float psum = 0.0f, pmx = -INFINITY, pmn = INFINITY;
#pragma unroll
                    for (int j = 0; j < 8; ++j) {
                        const float d  = xcur[j] - w[row][j];
                        const float mv = c1 * fabsf(d) + c2 * m[row][j];
                        w[row][j] += lr * d;
                        m[row][j] = mv;
                        psum += mv;
                        pmx = fmaxf(pmx, mv);
                        pmn = fminf(pmn, mv);
                    }
                    psum = wave_sum_f(psum); pmx = wave_max_f(pmx); pmn = wave_min_f(pmn);
                    if (lane == 0) { sf[0][wid] = psum; sf[1][wid] = pmx; sf[2][wid] = pmn; }
                    __syncthreads();
                    const float ts  = sf[0][0] + sf[0][1] + sf[0][2] + sf[0][3];
                    const float tmx = fmaxf(fmaxf(sf[1][0], sf[1][1]), fmaxf(sf[1][2], sf[1][3]));
                    const float tmn = fminf(fminf(sf[2][0], sf[2][1]), fminf(sf[2][2], sf[2][3]));
                    __syncthreads();
                    const float av    = ts * (1.0f / (float)DD);
                    const float denom = kEPS * (tmx - tmn);
                    if (denom == 0.0f) {
#pragma unroll
                        for (int j = 0; j < 8; ++j) r[row][j] = 1.0f;
                    } else {
#pragma unroll
                        for (int j = 0; j < 8; ++j) {
                            float a = (m[row][j] - av) / denom;
                            a = fminf(fmaxf(a, -80.0f), 80.0f);
                            r[row][j] = 1.0f / (1.0f + expf(a));
                        }
                    }
                }
            }
        }

        if (t < BB - 1) {
#pragma unroll
            for (int j = 0; j < 8; ++j) xcur[j] = xnext[j];
            post_key(t + 1);
            if (t < BB - 2) {   // prefetch x(t+2): overlaps the next spin-wait
                const size_t xb = (size_t)(t + 2) * DD + col;
                *(float4*)(xnext)     = *(const float4*)(x + xb);
                *(float4*)(xnext + 4) = *(const float4*)(x + xb + 4);
            }
        }
    }

#pragma unroll
    for (int row = 0; row < RPB; ++row) {
        const size_t base = (size_t)(n0 + row) * DD + col;
        *(float4*)(Wout + base)     = *(float4*)(&w[row][0]);
        *(float4*)(Wout + base + 4) = *(float4*)(&w[row][4]);
    }
}

// ---------------------------------------------------------------------------
// Fallback: proven round-3 per-step kernel (65 dispatches, ~1.7 ms).
// ---------------------------------------------------------------------------
__global__ __launch_bounds__(256) void som_step(
    const float* __restrict__ x_upd, const float* __restrict__ x_act,
    float* __restrict__ W, float* __restrict__ M, float* __restrict__ R,
    const void* __restrict__ nb, const unsigned* __restrict__ flag,
    const unsigned long long* __restrict__ part_upd,
    unsigned long long* __restrict__ part_act)
{
    const int n   = blockIdx.x;
    const int tid = threadIdx.x;
    __shared__ float  sred[3][4];
    __shared__ double sredd[2][4];

    float lr = 0.0f;
    if (part_upd != nullptr) {
        unsigned long long k = part_upd[(size_t)(tid & 63) * 8];
        k = wave_max_u64(k);
        const double act_w = __longlong_as_double((long long)(k & ~0xFFFULL));
        const int winner   = 4095 - (int)(k & 0xFFFULL);
        if (act_w >= (double)kAT) {
            if (n == winner) lr = kEB;
            else {
                const size_t off = (size_t)winner * NN + n;
                const bool isnb = (*flag != 0)
                    ? (((const unsigned char*)nb)[off] != 0)
                    : (((const int*)nb)[off] != 0);
                if (isnb) lr = kEN;
            }
        }
    }
    const bool next = (x_act != nullptr);
    if (lr == 0.0f && !next) return;

    const size_t rowoff = (size_t)n * DD + (size_t)tid * 8;
    const size_t xoff   = (size_t)tid * 8;
    float w[8], r[8];
    *(float4*)(w)     = *(const float4*)(W + rowoff);
    *(float4*)(w + 4) = *(const float4*)(W + rowoff + 4);

    if (lr != 0.0f) {
        float m[8], xu[8], mnew[8];
        *(float4*)(m)      = *(const float4*)(M + rowoff);
        *(float4*)(m + 4)  = *(const float4*)(M + rowoff + 4);
        *(float4*)(xu)     = *(const float4*)(x_upd + xoff);
        *(float4*)(xu + 4) = *(const float4*)(x_upd + xoff + 4);
        const float c1 = lr * kDSBETA, c2 = 1.0f - c1;
        float psum = 0.0f, pmx = -INFINITY, pmn = INFINITY;
#pragma unroll
        for (int j = 0; j < 8; j++) {
            const float d = xu[j] - w[j];
            w[j] += lr * d;
            const float mv = c1 * fabsf(d) + c2 * m[j];
            mnew[j] = mv; psum += mv;
            pmx = fmaxf(pmx, mv); pmn = fminf(pmn, mv);
        }
        psum = wave_sum_f(psum); pmx = wave_max_f(pmx); pmn = wave_min_f(pmn);
        const int wid = tid >> 6, lane = tid & 63;
        if (lane == 0) { sred[0][wid] = psum; sred[1][wid] = pmx; sred[2][wid] = pmn; }
        __syncthreads();
        const float ts  = sred[0][0] + sred[0][1] + sred[0][2] + sred[0][3];
        const float tmx = fmaxf(fmaxf(sred[1][0], sred[1][1]), fmaxf(sred[1][2], sred[1][3]));
        const float tmn = fminf(fminf(sred[2][0], sred[2][1]), fminf(sred[2][2], sred[2][3]));
        __syncthreads();
        const float av = ts * (1.0f / (float)DD);
        const float denom = kEPS * (tmx - tmn);
        if (denom == 0.0f) {
#pragma unroll
            for (int j = 0; j < 8; j++) r[j] = 1.0f;
        } else {
#pragma unroll
            for (int j = 0; j < 8; j++) {
                float a = (mnew[j] - av) / denom;
                a = fminf(fmaxf(a, -80.0f), 80.0f);
                r[j] = 1.0f / (1.0f + expf(a));
            }
        }
        *(float4*)(W + rowoff)     = *(float4*)(w);
        *(float4*)(W + rowoff + 4) = *(float4*)(w + 4);
        *(float4*)(M + rowoff)     = *(float4*)(mnew);
        *(float4*)(M + rowoff + 4) = *(float4*)(mnew + 4);
        *(float4*)(R + rowoff)     = *(float4*)(r);
        *(float4*)(R + rowoff + 4) = *(float4*)(r + 4);
    } else {
        *(float4*)(r)     = *(const float4*)(R + rowoff);
        *(float4*)(r + 4) = *(const float4*)(R + rowoff + 4);
    }

    if (next) {
        float xn[8];
        *(float4*)(xn)     = *(const float4*)(x_act + xoff);
        *(float4*)(xn + 4) = *(const float4*)(x_act + xoff + 4);
        double pd = 0.0, ps = 0.0;
#pragma unroll
        for (int j = 0; j < 8; j++) {
            const double d  = (double)xn[j] - (double)w[j];
            const double rj = (double)r[j];
            pd += rj * d * d; ps += rj;
        }
        pd = wave_sum_d(pd); ps = wave_sum_d(ps);
        const int wid = tid >> 6, lane = tid & 63;
        if (lane == 0) { sredd[0][wid] = pd; sredd[1][wid] = ps; }
        __syncthreads();
        if (tid == 0) {
            const double td = sredd[0][0] + sredd[0][1] + sredd[0][2] + sredd[0][3];
            const double tr = sredd[1][0] + sredd[1][1] + sredd[1][2] + sredd[1][3];
            const double act = tr / (tr + td + 1e-7);
            const unsigned long long ab = (unsigned long long)__double_as_longlong(act);
            const unsigned long long kk = (ab & ~0xFFFULL) | (unsigned long long)(4095 - n);
            atomicMax(&part_act[(size_t)(n & 63) * 8], kk);
        }
    }
}

extern "C" void kernel_launch(void* const* d_in, const int* in_sizes, int n_in,
                              void* d_out, int out_size, void* d_ws, size_t ws_size,
                              hipStream_t stream) {
    const float*         x   = (const float*)d_in[0];
    const float*         W0  = (const float*)d_in[1];
    float*               M   = (float*)d_in[2];
    float*               R   = (float*)d_in[3];
    const unsigned char* nbb = (const unsigned char*)d_in[5];
    float*               W   = (float*)d_out;

    // ws layout (regions overlap across the two exclusive paths):
    //   region A (270,336 B): persist `keys` (64x512 u64) / fallback `part`
    //   region B ( 32,768 B): persist `wkey` broadcast copies
    //   flag     (       4 B)
    const size_t regA = (size_t)66 * 64 * 8 * sizeof(unsigned long long);
    const size_t regB = (size_t)BB * 8 * 8 * sizeof(unsigned long long);
    unsigned long long* keys  = (unsigned long long*)d_ws;
    unsigned long long* wkey  = (unsigned long long*)((char*)d_ws + regA);
    unsigned*           flagp = (unsigned*)((char*)d_ws + regA + regB);

    hipMemsetAsync(d_ws, 0, regA + regB + 64, stream);
    detect_nb<<<1, 256, 0, stream>>>(nbb, flagp);

    // persistent path requires all 512 blocks co-resident (2 blocks/CU)
    int occ = 0;
    hipError_t qerr = hipOccupancyMaxActiveBlocksPerMultiprocessor(
        &occ, (const void*)som_persist, 256, 0);
    if (qerr == hipSuccess && occ >= 2) {
        som_persist<<<NBLK, 256, 0, stream>>>(x, W0, M, R, nbb, flagp, W, keys, wkey);
        return;
    }

    // ---- fallback: proven 65-dispatch path ----
    unsigned long long* part = keys;
    hipMemcpyAsync(W, W0, sizeof(float) * (size_t)NN * DD, hipMemcpyDeviceToDevice, stream);
    som_step<<<NN, 256, 0, stream>>>(nullptr, x, W, M, R, nbb, flagp, nullptr, part);
    for (int t = 0; t < BB; t++) {
        const float* xu = x + (size_t)t * DD;
        const float* xa = (t < BB - 1) ? (x + (size_t)(t + 1) * DD) : nullptr;
        const unsigned long long* pu = part + (size_t)t * 64 * 8;
        unsigned long long*       pa = (t < BB - 1) ? (part + (size_t)(t + 1) * 64 * 8) : nullptr;
        som_step<<<NN, 256, 0, stream>>>(xu, xa, W, M, R, nbb, flagp, pu, pa);
    }
}